// Round 2
// baseline (999.399 us; speedup 1.0000x reference)
//
#include <hip/hip_runtime.h>
#include <stdint.h>

static constexpr int BB = 8;
static constexpr int SS = 4096;
static constexpr int HH = 1024;

// ---- monotonic float<->uint mapping (order-preserving, for atomicMax) ----
__device__ __forceinline__ unsigned f2mono(float f) {
    unsigned u = __float_as_uint(f);
    return (u & 0x80000000u) ? ~u : (u | 0x80000000u);
}
__device__ __forceinline__ float mono2f(unsigned u) {
    return __uint_as_float((u & 0x80000000u) ? (u ^ 0x80000000u) : ~u);
}

// ---- kernel I: zero scores, copy previous_mask -> out_mask ----
__global__ void k_init(const float* __restrict__ prev, unsigned* __restrict__ scores,
                       float* __restrict__ out_mask) {
    int i = blockIdx.x * blockDim.x + threadIdx.x;
    if (i < BB * SS) { scores[i] = 0u; out_mask[i] = prev[i]; }
}

// ---- kernel 0: amin over attention_mask, bmax over bias ----
__global__ void reduce_ab(const float* __restrict__ a, const float* __restrict__ bias,
                          float* __restrict__ amin_out, float* __restrict__ bmax_out) {
    __shared__ float red[256];
    int t = threadIdx.x;
    float mn = 1e30f;
    const float4* a4 = (const float4*)a;
    for (int i = t; i < BB * SS / 4; i += 256) {
        float4 v = a4[i];
        mn = fminf(mn, fminf(fminf(v.x, v.y), fminf(v.z, v.w)));
    }
    red[t] = mn; __syncthreads();
    for (int o = 128; o; o >>= 1) { if (t < o) red[t] = fminf(red[t], red[t + o]); __syncthreads(); }
    if (t == 0) *amin_out = red[0];
    __syncthreads();
    float mx = -1e30f;
    for (int i = t; i < HH; i += 256) mx = fmaxf(mx, bias[i]);
    red[t] = mx; __syncthreads();
    for (int o = 128; o; o >>= 1) { if (t < o) red[t] = fmaxf(red[t], red[t + o]); __syncthreads(); }
    if (t == 0) *bmax_out = red[0];
}

// ---- kernel A: per-batch-row compaction (one 64-lane wave per row) ----
__global__ void compact(const float* __restrict__ prev, const float* __restrict__ a,
                        int* __restrict__ kept_src,
                        int* __restrict__ n_keep, int* __restrict__ zcnt) {
    int b = blockIdx.x;
    int lane = threadIdx.x;          // 0..63, one wave
    const float* pm = prev + (size_t)b * SS;
    const float* am = a + (size_t)b * SS;
    int* ks = kept_src + (size_t)b * SS;

    int base_s = lane * (SS / 64);   // 64 contiguous elements per lane
    int cnt = 0, zc = 0;
    for (int i = 0; i < SS / 64; ++i) {
        if (pm[base_s + i] > 0.5f) {
            cnt++;
            if (am[base_s + i] == 0.0f) zc++;
        }
    }
    int incl = cnt;
    for (int o = 1; o < 64; o <<= 1) {
        int v = __shfl_up(incl, o);
        if (lane >= o) incl += v;
    }
    int total = __shfl(incl, 63);
    int pos = incl - cnt;
    for (int i = 0; i < SS / 64; ++i) {
        if (pm[base_s + i] > 0.5f) ks[pos++] = base_s + i;
    }
    for (int o = 1; o < 64; o <<= 1) zc += __shfl_xor(zc, o);
    if (lane == 0) { n_keep[b] = total; zcnt[b] = zc; }
    for (int j = total + lane; j < SS; j += 64) ks[j] = 0;   // pad with safe dummy
}

// ---- kernel B: gathered GEMM + bias + max-over-columns -> atomicMax(score) ----
// 64x256 tile, 256 threads (4 waves). wave w: rows w*16..w*16+15; lane: 4 cols.
// Per k-step: 64 FMA + 4 broadcast ds_read_b128 + 1 global float4.
#define BM 64
#define BN 256
#define BK 32
#define LDA 68   // padded stride, rows stay 16B-aligned
__global__ __launch_bounds__(256) void gemm_max(
    const float* __restrict__ hs, const float* __restrict__ W,
    const float* __restrict__ bias, const int* __restrict__ kept_src,
    const int* __restrict__ n_keep, unsigned* __restrict__ scores) {
    int mt = blockIdx.x, nt = blockIdx.y, b = blockIdx.z;
    int nk = n_keep[b];
    int m0 = mt * BM;
    if (m0 >= nk) return;

    __shared__ float A[BK][LDA];
    __shared__ int src[BM];
    int t = threadIdx.x;
    int lane = t & 63, w = t >> 6;
    if (t < BM) src[t] = kept_src[(size_t)b * SS + m0 + t];
    __syncthreads();

    int srow = t >> 2;               // 0..63: staging row
    int skq  = t & 3;                // 8-float group within the 32-k chunk
    const float* arow = hs + ((size_t)b * SS + (size_t)src[srow]) * HH + skq * 8;
    int n0 = nt * BN;
    const float* wcol = W + n0 + lane * 4;

    float acc[16][4];
#pragma unroll
    for (int r = 0; r < 16; ++r)
#pragma unroll
        for (int c = 0; c < 4; ++c) acc[r][c] = 0.f;

    for (int kc = 0; kc < HH / BK; ++kc) {
        // issue next A chunk loads early (latency hides under prior compute)
        float4 f0 = *(const float4*)(arow + kc * BK);
        float4 f1 = *(const float4*)(arow + kc * BK + 4);
        __syncthreads();             // previous chunk's compute done
        int kb = skq * 8;
        A[kb + 0][srow] = f0.x; A[kb + 1][srow] = f0.y;
        A[kb + 2][srow] = f0.z; A[kb + 3][srow] = f0.w;
        A[kb + 4][srow] = f1.x; A[kb + 5][srow] = f1.y;
        A[kb + 6][srow] = f1.z; A[kb + 7][srow] = f1.w;
        __syncthreads();
        const float* wk = wcol + (size_t)kc * BK * HH;
#pragma unroll 4
        for (int k = 0; k < BK; ++k) {
            float4 w4 = *(const float4*)wk;
            wk += HH;
            const float4* ap = (const float4*)(&A[k][w * 16]);  // wave-uniform -> broadcast
            float4 a0 = ap[0], a1 = ap[1], a2 = ap[2], a3 = ap[3];
            float av[16] = {a0.x, a0.y, a0.z, a0.w, a1.x, a1.y, a1.z, a1.w,
                            a2.x, a2.y, a2.z, a2.w, a3.x, a3.y, a3.z, a3.w};
            float wv[4] = {w4.x, w4.y, w4.z, w4.w};
#pragma unroll
            for (int r = 0; r < 16; ++r)
#pragma unroll
                for (int c = 0; c < 4; ++c)
                    acc[r][c] = fmaf(av[r], wv[c], acc[r][c]);
        }
    }

    float4 bia = *(const float4*)(bias + n0 + lane * 4);
    float bv[4] = {bia.x, bia.y, bia.z, bia.w};
#pragma unroll
    for (int r = 0; r < 16; ++r) {
        float v = -1e30f;
#pragma unroll
        for (int c = 0; c < 4; ++c) v = fmaxf(v, acc[r][c] + bv[c]);
        for (int o = 32; o; o >>= 1) v = fmaxf(v, __shfl_xor(v, o));
        if (lane == 0)
            atomicMax(scores + (size_t)b * SS + m0 + w * 16 + r, f2mono(v));
    }
}

// ---- kernel C: exact stable top-k via rank counting + scatter ----
// grid (BB, 4): each block ranks 1024 elements of row b against all 4096.
__global__ __launch_bounds__(1024) void topk_rank(
    const float* __restrict__ a, const int* __restrict__ kept_src,
    const unsigned* __restrict__ scores, const int* __restrict__ n_keep,
    const int* __restrict__ zcnt, const float* __restrict__ amin_p,
    const float* __restrict__ bmax_p, float* __restrict__ out_mask) {
    __shared__ unsigned long long keys[SS];   // 32 KiB
    int b = blockIdx.x, ch = blockIdx.y, t = threadIdx.x;
    int nk = n_keep[b];
    float amin = *amin_p, bmax = *bmax_p;
    int z = zcnt[b] + ((amin == 0.0f) ? (SS - nk) : 0);
    int tk = (int)((float)z * 0.8f);
    if (tk < 1) tk = 1;
    float padv = (bmax + amin * 100.0f) + amin;

    const int* ks = kept_src + (size_t)b * SS;
    const unsigned* sc = scores + (size_t)b * SS;
    const float* arow = a + (size_t)b * SS;

    for (int j = t; j < SS; j += 1024) {
        float sval;
        if (j < nk) {
            float core = mono2f(sc[j]);
            float av = arow[ks[j]];
            sval = (core + av * 100.0f) + av;     // replicate reference op order
        } else {
            sval = padv;
        }
        // ascending key = (value desc, index asc), unique per j -> stable
        keys[j] = ((unsigned long long)(~f2mono(sval)) << 32) | (unsigned)j;
    }
    __syncthreads();

    int j = ch * 1024 + t;
    unsigned long long mykey = keys[j];
    int rank = 0;
#pragma unroll 8
    for (int i = 0; i < SS; ++i) rank += (keys[i] < mykey) ? 1 : 0;

    if (j < nk) out_mask[(size_t)b * SS + ks[j]] = (rank < tk) ? 1.0f : 0.0f;
}

extern "C" void kernel_launch(void* const* d_in, const int* in_sizes, int n_in,
                              void* d_out, int out_size, void* d_ws, size_t ws_size,
                              hipStream_t stream) {
    const float* hs   = (const float*)d_in[0];   // [8,4096,1024]
    const float* am   = (const float*)d_in[1];   // [8,4096]
    const float* pmsk = (const float*)d_in[2];   // [8,4096]
    const float* W    = (const float*)d_in[3];   // [1024,1024]
    const float* bias = (const float*)d_in[4];   // [1024]

    float* out0 = (float*)d_out;                       // new_ret
    float* out1 = out0 + (size_t)BB * SS * HH;         // new_mask

    char* ws = (char*)d_ws;
    int*      kept_src = (int*)ws;                                // 128 KiB
    unsigned* scores   = (unsigned*)(ws + (size_t)BB * SS * 4);   // 128 KiB
    int*      nkeep    = (int*)(ws + (size_t)2 * BB * SS * 4);
    int*      zc       = nkeep + BB;
    float*    amin_p   = (float*)(zc + BB);
    float*    bmax_p   = amin_p + 1;

    // output 0: new_ret == hidden_states exactly
    hipMemcpyAsync(out0, hs, (size_t)BB * SS * HH * sizeof(float),
                   hipMemcpyDeviceToDevice, stream);

    hipLaunchKernelGGL(k_init, dim3(BB * SS / 256), dim3(256), 0, stream,
                       pmsk, scores, out1);
    hipLaunchKernelGGL(reduce_ab, dim3(1), dim3(256), 0, stream, am, bias, amin_p, bmax_p);
    hipLaunchKernelGGL(compact, dim3(BB), dim3(64), 0, stream,
                       pmsk, am, kept_src, nkeep, zc);
    hipLaunchKernelGGL(gemm_max, dim3(SS / BM, HH / BN, BB), dim3(256), 0, stream,
                       hs, W, bias, kept_src, nkeep, scores);
    hipLaunchKernelGGL(topk_rank, dim3(BB, SS / 1024), dim3(1024), 0, stream,
                       am, kept_src, scores, nkeep, zc, amin_p, bmax_p, out1);
}